// Round 5
// baseline (369.240 us; speedup 1.0000x reference)
//
#include <hip/hip_runtime.h>
#include <hip/hip_cooperative_groups.h>

namespace cg = cooperative_groups;

typedef __attribute__((ext_vector_type(8))) _Float16 f16x8;
typedef __attribute__((ext_vector_type(4))) _Float16 f16x4;
typedef __attribute__((ext_vector_type(4))) float f32x4;

#define D 128
#define NCH 256     // Pab channels: [0:128)=Pa'=Pa+b1, [128:256)=Pb
#define NBAUX 256   // cooperative aux grid

static __device__ __forceinline__ ushort f2h(float f) {
    _Float16 h = (_Float16)f;
    return __builtin_bit_cast(ushort, h);
}

// ================= cooperative aux kernel =================
// phase 0: zero out_enc + hist, convert weights
// phase 1: col histogram
// phase 2: exclusive scan of hist -> ofs
// phase 3: counting-sort scatter -> spair (col,row)
// phase 4: pab = x(fp16) @ [W1a | W1b] (+b1 folded into Pa')
__global__ __launch_bounds__(256) void aux_coop(
    const float* __restrict__ x,
    const float* __restrict__ W1,
    const float* __restrict__ W2,
    const float* __restrict__ b1,
    const int* __restrict__ erow,
    const int* __restrict__ ecol,
    ushort* __restrict__ w1abt,
    ushort* __restrict__ w2t,
    ushort* __restrict__ pab,
    int* __restrict__ hist,
    int* __restrict__ partial,
    int* __restrict__ ofs,
    int2* __restrict__ spair,
    unsigned int* __restrict__ out_enc,
    int E, int n_nodes, int out_n)
{
    cg::grid_group grid = cg::this_grid();
    const int tid = threadIdx.x;
    const int bid = blockIdx.x;
    const int gthreads = gridDim.x * 256;
    const int gtid = bid * 256 + tid;

    __shared__ int s[256];
    __shared__ ushort A[64 * 128];   // pab staging tile (phase 4)

    // ---- phase 0: zero output (encoded) + hist, convert weights
    {
        const int n4 = out_n >> 2;
        for (int i = gtid; i < n4; i += gthreads)
            ((uint4*)out_enc)[i] = make_uint4(0u, 0u, 0u, 0u);
        for (int i = gtid; i < n_nodes; i += gthreads)
            hist[i] = 0;
        if (gtid < NCH * D) {
            int oc = gtid >> 7, k = gtid & 127;
            float v;
            if (oc < 128) v = W1[k * D + oc] - W1[(k + 128) * D + oc];
            else          v = W1[(k + 128) * D + (oc - 128)];
            w1abt[gtid] = f2h(v);
        } else if (gtid < NCH * D + D * D) {
            int id2 = gtid - NCH * D;
            int oc = id2 >> 7, k = id2 & 127;
            w2t[id2] = f2h(W2[k * D + oc]);
        }
    }
    grid.sync();

    // ---- phase 1: histogram of cols
    for (int e = gtid; e < E; e += gthreads) {
        int c = ecol[e];
        if ((unsigned)c >= (unsigned)n_nodes) c = 0;
        atomicAdd(&hist[c], 1);
    }
    grid.sync();

    // ---- phase 2a: per-block inclusive scan (65536 threads cover n_nodes)
    int v = (gtid < n_nodes) ? hist[gtid] : 0;
    s[tid] = v;
    __syncthreads();
    #pragma unroll
    for (int off = 1; off < 256; off <<= 1) {
        int t = (tid >= off) ? s[tid - off] : 0;
        __syncthreads();
        s[tid] += t;
        __syncthreads();
    }
    int excl = s[tid] - v;
    if (tid == 255) partial[bid] = s[tid];
    grid.sync();

    // ---- phase 2b: block 0 scans block sums (in-place -> exclusive)
    if (bid == 0) {
        int w0 = partial[tid];
        __syncthreads();
        s[tid] = w0;
        __syncthreads();
        #pragma unroll
        for (int off = 1; off < 256; off <<= 1) {
            int t = (tid >= off) ? s[tid - off] : 0;
            __syncthreads();
            s[tid] += t;
            __syncthreads();
        }
        partial[tid] = s[tid] - w0;
    }
    grid.sync();

    // ---- phase 2c: write global exclusive offsets
    if (gtid < n_nodes) ofs[gtid] = partial[bid] + excl;
    grid.sync();

    // ---- phase 3: scatter (counting sort; max is order-independent)
    for (int e = gtid; e < E; e += gthreads) {
        int c = ecol[e];
        if ((unsigned)c >= (unsigned)n_nodes) c = 0;
        int r = erow[e];
        if ((unsigned)r >= (unsigned)n_nodes) r = 0;
        int pos = atomicAdd(&ofs[c], 1);
        spair[pos] = make_int2(c, r);
    }

    // ---- phase 4: pab tiles (needs w1abt from phase 0; independent of scatter)
    const int ntiles = (n_nodes + 63) >> 6;
    const int l = tid & 63, w = tid >> 6;
    const int l15 = l & 15, lq = l >> 4;
    for (int t = bid; t < ntiles; t += gridDim.x) {
        const int base = t * 64;
        __syncthreads();
        #pragma unroll
        for (int it = 0; it < 8; ++it) {
            int idx4 = it * 256 + tid;       // float4 index in 64x128 tile
            int row = idx4 >> 5;
            int c4  = idx4 & 31;
            int node = base + row;
            float4 vx = make_float4(0.f, 0.f, 0.f, 0.f);
            if (node < n_nodes) vx = ((const float4*)x)[(size_t)node * 32 + c4];
            f16x4 o;
            o[0] = (_Float16)vx.x; o[1] = (_Float16)vx.y;
            o[2] = (_Float16)vx.z; o[3] = (_Float16)vx.w;
            *(f16x4*)((char*)A + row * 256 + ((c4 * 8) ^ ((row & 7) << 4))) = o;
        }
        __syncthreads();

        f32x4 acc[4][4];                 // [channel frag][node frag]
        #pragma unroll
        for (int cf = 0; cf < 4; ++cf)
            #pragma unroll
            for (int rf = 0; rf < 4; ++rf)
                acc[cf][rf] = (f32x4){0.f, 0.f, 0.f, 0.f};

        #pragma unroll
        for (int kk = 0; kk < 4; ++kk) {
            f16x8 a[4], b[4];
            #pragma unroll
            for (int cf = 0; cf < 4; ++cf)
                a[cf] = *(const f16x8*)(w1abt + (w * 64 + cf * 16 + l15) * 128 + kk * 32 + lq * 8);
            #pragma unroll
            for (int rf = 0; rf < 4; ++rf) {
                int row = rf * 16 + l15;
                b[rf] = *(const f16x8*)((const char*)A + row * 256 + ((kk * 64 + lq * 16) ^ ((row & 7) << 4)));
            }
            #pragma unroll
            for (int cf = 0; cf < 4; ++cf)
                #pragma unroll
                for (int rf = 0; rf < 4; ++rf)
                    acc[cf][rf] = __builtin_amdgcn_mfma_f32_16x16x32_f16(a[cf], b[rf], acc[cf][rf], 0, 0, 0);
        }

        // D[ch][node]: node = rf*16 + l15 (lane), ch = w*64 + cf*16 + lq*4 + r
        #pragma unroll
        for (int rf = 0; rf < 4; ++rf) {
            int node = base + rf * 16 + l15;
            if (node < n_nodes) {
                #pragma unroll
                for (int cf = 0; cf < 4; ++cf) {
                    int ch = w * 64 + cf * 16 + lq * 4;
                    float4 bb = (w < 2) ? *(const float4*)(b1 + ch) : make_float4(0.f, 0.f, 0.f, 0.f);
                    f16x4 o;
                    o[0] = (_Float16)(acc[cf][rf][0] + bb.x);
                    o[1] = (_Float16)(acc[cf][rf][1] + bb.y);
                    o[2] = (_Float16)(acc[cf][rf][2] + bb.z);
                    o[3] = (_Float16)(acc[cf][rf][3] + bb.w);
                    *(f16x4*)(pab + (size_t)node * NCH + ch) = o;
                }
            }
        }
    }
}

// ================= main fused kernel: 128 sorted edges per block =================
__global__ __launch_bounds__(256, 4) void edgeconv_main(
    const ushort* __restrict__ pab,
    const ushort* __restrict__ w2t,
    const int2* __restrict__ spair,
    unsigned int* __restrict__ out_enc,
    int E, int n_nodes)
{
    __shared__ char smem[128 * 256];     // 32KB: Hs fp16[128][128] (swz) -> Mf f32[128][64] halves
    __shared__ int colidx[128];
    __shared__ int rowidx[128];
    __shared__ unsigned char starts[128];
    __shared__ int nruns_s, nvalid_s;

    const int tid = threadIdx.x;

    // XCD-bijective swizzle: consecutive sorted tiles -> same XCD L2
    const int nwg = gridDim.x, orig = blockIdx.x;
    const int q = nwg >> 3, rr = nwg & 7, xcd = orig & 7;
    const int wgid = (xcd < rr ? xcd * (q + 1) : rr * (q + 1) + (xcd - rr) * q) + (orig >> 3);
    const int e0 = wgid * 128;

    if (tid < 128) {
        int idx = e0 + tid;
        int2 p = (idx < E) ? spair[idx] : make_int2(-1, 0);
        colidx[tid] = p.x;
        rowidx[tid] = p.y;
    }
    __syncthreads();

    // run detection over 128 sorted cols (wave 0; two 64-lane ballots)
    if (tid < 64) {
        int c0 = colidx[tid], c1 = colidx[64 + tid];
        bool v0 = (c0 >= 0), v1 = (c1 >= 0);
        bool s0 = v0 && (tid == 0 || colidx[tid - 1] != c0);
        bool s1 = v1 && (colidx[63 + tid] != c1);
        unsigned long long mb0 = __ballot(s0);
        unsigned long long mb1 = __ballot(s1);
        unsigned long long vb0 = __ballot(v0);
        unsigned long long vb1 = __ballot(v1);
        int n0 = __popcll(mb0);
        if (tid == 0) {
            nruns_s = n0 + __popcll(mb1);
            nvalid_s = __popcll(vb0) + __popcll(vb1);
        }
        unsigned long long below = (1ull << tid) - 1ull;
        if (s0) starts[__popcll(mb0 & below)] = (unsigned char)tid;
        if (s1) starts[n0 + __popcll(mb1 & below)] = (unsigned char)(64 + tid);
    }

    // ---- phase 1: h = relu(Pa'[col] + Pb[row]) -> Hs (fp16, swizzled)
    ushort* Hs = (ushort*)smem;
    {
        const int cg   = tid & 15;      // 16 threads per edge -> coalesced 256B per side
        const int esub = tid >> 4;
        const f16x8 zero = {0, 0, 0, 0, 0, 0, 0, 0};
        f16x8 va[8], vb[8];
        #pragma unroll
        for (int it = 0; it < 8; ++it) {
            int e = it * 16 + esub;
            int c = colidx[e]; if (c < 0) c = 0;
            int r = rowidx[e];
            va[it] = *(const f16x8*)(pab + (size_t)c * NCH + cg * 8);
            vb[it] = *(const f16x8*)(pab + (size_t)r * NCH + 128 + cg * 8);
        }
        #pragma unroll
        for (int it = 0; it < 8; ++it) {
            int e = it * 16 + esub;
            f16x8 h = va[it] + vb[it];
            h = __builtin_elementwise_max(h, zero);
            *(f16x8*)((char*)Hs + e * 256 + ((cg * 16) ^ ((e & 7) << 4))) = h;
        }
    }
    __syncthreads();

    const int l = tid & 63, w = tid >> 6;
    const int wr = w >> 1, wc = w & 1;
    const int l15 = l & 15, lq = l >> 4;
    const int mr = wr * 64;

    // ---- layer 2: [128x128] @ [128x128] -> msg; each wave 64x64
    f32x4 acc2[4][4];
    #pragma unroll
    for (int mf = 0; mf < 4; ++mf)
        #pragma unroll
        for (int nf = 0; nf < 4; ++nf)
            acc2[mf][nf] = (f32x4){0.f, 0.f, 0.f, 0.f};

    #pragma unroll
    for (int kk = 0; kk < 4; ++kk) {
        f16x8 a[4], b[4];
        #pragma unroll
        for (int mf = 0; mf < 4; ++mf) {
            int row = mr + mf * 16 + l15;
            a[mf] = *(const f16x8*)((const char*)Hs + row * 256 + ((kk * 64 + lq * 16) ^ ((row & 7) << 4)));
        }
        #pragma unroll
        for (int nf = 0; nf < 4; ++nf) {
            int wcol = wc * 64 + nf * 16 + l15;
            b[nf] = *(const f16x8*)(w2t + wcol * 128 + kk * 32 + lq * 8);
        }
        #pragma unroll
        for (int mf = 0; mf < 4; ++mf)
            #pragma unroll
            for (int nf = 0; nf < 4; ++nf)
                acc2[mf][nf] = __builtin_amdgcn_mfma_f32_16x16x32_f16(a[mf], b[nf], acc2[mf][nf], 0, 0, 0);
    }

    // ---- two col-halves: stage M (f32, swizzled, overlaying Hs), segmented max, atomic per (run,col)
    float* Mf = (float*)smem;
    #pragma unroll
    for (int half = 0; half < 2; ++half) {
        __syncthreads();                 // all reads of smem from previous phase done
        if (wc == half) {
            #pragma unroll
            for (int nf = 0; nf < 4; ++nf)
                #pragma unroll
                for (int mf = 0; mf < 4; ++mf)
                    #pragma unroll
                    for (int r = 0; r < 4; ++r) {
                        int row = mr + mf * 16 + lq * 4 + r;
                        int cl = nf * 16 + l15;
                        *(float*)((char*)Mf + row * 256 + ((cl * 4) ^ ((row & 7) << 4))) =
                            acc2[mf][nf][r];
                    }
        }
        __syncthreads();
        {
            const int c = tid & 63, g = tid >> 6;
            const int nruns = nruns_s, nvalid = nvalid_s;
            for (int k = g; k < nruns; k += 4) {
                int s  = starts[k];
                int e_ = (k + 1 < nruns) ? (int)starts[k + 1] : nvalid;
                float m = -INFINITY;
                for (int r2 = s; r2 < e_; ++r2)
                    m = fmaxf(m, *(const float*)((const char*)Mf + r2 * 256 + ((c * 4) ^ ((r2 & 7) << 4))));
                int node = colidx[s];
                unsigned bs = __float_as_uint(m);
                unsigned enc = (bs & 0x80000000u) ? ~bs : (bs | 0x80000000u);
                atomicMax(&out_enc[(size_t)node * D + half * 64 + c], enc);
            }
        }
    }
}

// ---------- decode: in-place on d_out; u==0 -> 0.0f (empty), else decode + b2[channel]
__global__ void decode_kernel(unsigned int* __restrict__ io, const float* __restrict__ b2, int n4)
{
    int gid = blockIdx.x * blockDim.x + threadIdx.x;
    if (gid < n4) {
        uint4 u = ((const uint4*)io)[gid];
        float4 bb = ((const float4*)b2)[gid & 31];
        float4 f;
        #define DEC(ux, b) ((ux) == 0u ? 0.f : ((((ux) & 0x80000000u) ? __uint_as_float((ux) & 0x7fffffffu) : __uint_as_float(~(ux))) + (b)))
        f.x = DEC(u.x, bb.x); f.y = DEC(u.y, bb.y); f.z = DEC(u.z, bb.z); f.w = DEC(u.w, bb.w);
        #undef DEC
        ((float4*)io)[gid] = f;
    }
}

extern "C" void kernel_launch(void* const* d_in, const int* in_sizes, int n_in,
                              void* d_out, int out_size, void* d_ws, size_t ws_size,
                              hipStream_t stream)
{
    const float* x  = (const float*)d_in[0];
    const int* eidx = (const int*)d_in[1];
    const float* W1 = (const float*)d_in[2];
    const float* b1 = (const float*)d_in[3];
    const float* W2 = (const float*)d_in[4];
    const float* b2 = (const float*)d_in[5];

    const int n_nodes = in_sizes[0] / D;
    const int E = in_sizes[1] / 2;
    const int* erow = eidx;        // edge_index[0]
    const int* ecol = eidx + E;    // edge_index[1]

    // ---- workspace layout
    char* ws = (char*)d_ws;
    size_t off = 0;
    ushort* pab = (ushort*)(ws + off);   off += (size_t)n_nodes * NCH * sizeof(ushort);
    off = (off + 255) & ~(size_t)255;
    ushort* w1abt = (ushort*)(ws + off); off += (size_t)NCH * D * sizeof(ushort);
    ushort* w2t = (ushort*)(ws + off);   off += (size_t)D * D * sizeof(ushort);
    off = (off + 255) & ~(size_t)255;
    int* hist = (int*)(ws + off);        off += (size_t)n_nodes * 4;
    off = (off + 255) & ~(size_t)255;
    int* ofs = (int*)(ws + off);         off += (size_t)n_nodes * 4;
    off = (off + 255) & ~(size_t)255;
    int* partial = (int*)(ws + off);     off += 256 * 4;
    off = (off + 255) & ~(size_t)255;
    int2* spair = (int2*)(ws + off);     off += (size_t)E * 8;

    unsigned int* out_enc = (unsigned int*)d_out;

    // ---- single cooperative aux dispatch
    {
        int E_v = E, nn_v = n_nodes, on_v = out_size;
        void* args[] = {
            (void*)&x, (void*)&W1, (void*)&W2, (void*)&b1,
            (void*)&erow, (void*)&ecol,
            (void*)&w1abt, (void*)&w2t, (void*)&pab,
            (void*)&hist, (void*)&partial, (void*)&ofs, (void*)&spair,
            (void*)&out_enc,
            (void*)&E_v, (void*)&nn_v, (void*)&on_v
        };
        hipLaunchCooperativeKernel((const void*)aux_coop, dim3(NBAUX), dim3(256),
                                   args, 0, stream);
    }

    const int nblocks = (E + 127) / 128;
    edgeconv_main<<<nblocks, 256, 0, stream>>>(pab, w2t, spair, out_enc, E, n_nodes);

    const int n4 = out_size / 4;
    decode_kernel<<<(n4 + 255) / 256, 256, 0, stream>>>(out_enc, b2, n4);
}

// Round 6
// 201.888 us; speedup vs baseline: 1.8289x; 1.8289x over previous
//
#include <hip/hip_runtime.h>

typedef __attribute__((ext_vector_type(8))) _Float16 f16x8;
typedef __attribute__((ext_vector_type(4))) _Float16 f16x4;
typedef __attribute__((ext_vector_type(4))) float f32x4;

#define D 128
#define NCH 256       // Pab channels: [0:128)=Pa'=Pa+b1, [128:256)=Pb
#define BNODES 32     // nodes per bucket (bucket = col >> 5)
#define TILE 64       // edges per inner tile in main

static __device__ __forceinline__ ushort f2h(float f) {
    _Float16 h = (_Float16)f;
    return __builtin_bit_cast(ushort, h);
}

// ---------- init: convert weights, zero bucket histogram ----------
__global__ void init_kernel(const float* __restrict__ W1,
                            const float* __restrict__ W2,
                            ushort* __restrict__ w1abt,
                            ushort* __restrict__ w2t,
                            int* __restrict__ hist,
                            int nbp)
{
    int gid = blockIdx.x * blockDim.x + threadIdx.x;
    if (gid < NCH * D) {
        int oc = gid >> 7, k = gid & 127;
        float v;
        if (oc < 128) v = W1[k * D + oc] - W1[(k + 128) * D + oc];
        else          v = W1[(k + 128) * D + (oc - 128)];
        w1abt[gid] = f2h(v);
    } else if (gid < NCH * D + D * D) {
        int id2 = gid - NCH * D;
        int oc = id2 >> 7, k = id2 & 127;
        w2t[id2] = f2h(W2[k * D + oc]);
    } else {
        int i = gid - (NCH * D + D * D);
        if (i < nbp) hist[i] = 0;
    }
}

// ---------- bucket histogram with LDS pre-aggregation ----------
__global__ __launch_bounds__(256) void hist_kernel(const int* __restrict__ ecol,
                                                   int* __restrict__ hist,
                                                   int E, int n_nodes, int nb)
{
    __shared__ int lh[1600];
    const int tid = threadIdx.x;
    for (int i = tid; i < nb; i += 256) lh[i] = 0;
    __syncthreads();
    const int stride = gridDim.x * 256;
    for (int e = blockIdx.x * 256 + tid; e < E; e += stride) {
        int c = ecol[e];
        if ((unsigned)c >= (unsigned)n_nodes) c = 0;
        atomicAdd(&lh[c >> 5], 1);
    }
    __syncthreads();
    for (int i = tid; i < nb; i += 256)
        if (lh[i]) atomicAdd(&hist[i], lh[i]);
}

// ---------- single-block scan over <=2048 bucket counts ----------
__global__ __launch_bounds__(1024) void scan_kernel(const int* __restrict__ hist,
                                                    int* __restrict__ ofs,
                                                    int* __restrict__ ocur,
                                                    int nb, int E)
{
    __shared__ int s[1024];
    const int tid = threadIdx.x;
    const int half = (nb + 1) >> 1;   // int2 pairs (hist padded even, zeroed)
    int2 v = make_int2(0, 0);
    if (tid < half) v = ((const int2*)hist)[tid];
    int sum = v.x + v.y;
    s[tid] = sum;
    __syncthreads();
    #pragma unroll
    for (int off = 1; off < 1024; off <<= 1) {
        int t = (tid >= off) ? s[tid - off] : 0;
        __syncthreads();
        s[tid] += t;
        __syncthreads();
    }
    int excl = s[tid] - sum;
    if (tid < half) {
        int i0 = 2 * tid;
        if (i0 < nb)     { ofs[i0] = excl;         ocur[i0] = excl; }
        if (i0 + 1 < nb) { ofs[i0 + 1] = excl + v.x; ocur[i0 + 1] = excl + v.x; }
    }
    if (tid == 0) ofs[nb] = E;
}

// ---------- scatter: counting sort by bucket; emit (col,row) pairs ----------
__global__ void scatter_kernel(const int* __restrict__ erow, const int* __restrict__ ecol,
                               int* __restrict__ ocur,
                               int2* __restrict__ spair,
                               int E, int n_nodes)
{
    int e = blockIdx.x * blockDim.x + threadIdx.x;
    if (e < E) {
        int c = ecol[e];
        if ((unsigned)c >= (unsigned)n_nodes) c = 0;
        int r = erow[e];
        if ((unsigned)r >= (unsigned)n_nodes) r = 0;
        int pos = atomicAdd(&ocur[c >> 5], 1);
        spair[pos] = make_int2(c, r);
    }
}

// ---------- Pab = x(fp16) @ [W1a | W1b] (+b1 folded into Pa'), fp16 out ----------
__global__ __launch_bounds__(256) void pab_kernel(
    const float* __restrict__ x,
    const ushort* __restrict__ w1abt,
    const float* __restrict__ b1,
    ushort* __restrict__ pab,
    int n_nodes)
{
    __shared__ ushort A[64 * 128];   // [node][k] fp16, swizzled
    const int tid = threadIdx.x;
    const int base = blockIdx.x * 64;

    #pragma unroll
    for (int it = 0; it < 8; ++it) {
        int idx4 = it * 256 + tid;       // float4 index in 64x128 tile
        int row = idx4 >> 5;
        int c4  = idx4 & 31;
        int node = base + row;
        float4 vx = make_float4(0.f, 0.f, 0.f, 0.f);
        if (node < n_nodes) vx = ((const float4*)x)[(size_t)node * 32 + c4];
        f16x4 o;
        o[0] = (_Float16)vx.x; o[1] = (_Float16)vx.y;
        o[2] = (_Float16)vx.z; o[3] = (_Float16)vx.w;
        *(f16x4*)((char*)A + row * 256 + ((c4 * 8) ^ ((row & 7) << 4))) = o;
    }
    __syncthreads();

    const int l = tid & 63, w = tid >> 6;
    const int l15 = l & 15, lq = l >> 4;

    f32x4 acc[4][4];                 // [channel frag][node frag]
    #pragma unroll
    for (int cf = 0; cf < 4; ++cf)
        #pragma unroll
        for (int rf = 0; rf < 4; ++rf)
            acc[cf][rf] = (f32x4){0.f, 0.f, 0.f, 0.f};

    #pragma unroll
    for (int kk = 0; kk < 4; ++kk) {
        f16x8 a[4], b[4];
        #pragma unroll
        for (int cf = 0; cf < 4; ++cf)
            a[cf] = *(const f16x8*)(w1abt + (w * 64 + cf * 16 + l15) * 128 + kk * 32 + lq * 8);
        #pragma unroll
        for (int rf = 0; rf < 4; ++rf) {
            int row = rf * 16 + l15;
            b[rf] = *(const f16x8*)((const char*)A + row * 256 + ((kk * 64 + lq * 16) ^ ((row & 7) << 4)));
        }
        #pragma unroll
        for (int cf = 0; cf < 4; ++cf)
            #pragma unroll
            for (int rf = 0; rf < 4; ++rf)
                acc[cf][rf] = __builtin_amdgcn_mfma_f32_16x16x32_f16(a[cf], b[rf], acc[cf][rf], 0, 0, 0);
    }

    // D[ch][node]: node = rf*16 + l15 (lane), ch = w*64 + cf*16 + lq*4 + r
    #pragma unroll
    for (int rf = 0; rf < 4; ++rf) {
        int node = base + rf * 16 + l15;
        if (node < n_nodes) {
            #pragma unroll
            for (int cf = 0; cf < 4; ++cf) {
                int ch = w * 64 + cf * 16 + lq * 4;
                float4 bb = (w < 2) ? *(const float4*)(b1 + ch) : make_float4(0.f, 0.f, 0.f, 0.f);
                f16x4 o;
                o[0] = (_Float16)(acc[cf][rf][0] + bb.x);
                o[1] = (_Float16)(acc[cf][rf][1] + bb.y);
                o[2] = (_Float16)(acc[cf][rf][2] + bb.z);
                o[3] = (_Float16)(acc[cf][rf][3] + bb.w);
                *(f16x4*)(pab + (size_t)node * NCH + ch) = o;
            }
        }
    }
}

// ================= main: one block owns one bucket (32 nodes), no global atomics =================
__global__ __launch_bounds__(256, 4) void edgeconv_main(
    const ushort* __restrict__ pab,
    const ushort* __restrict__ w2t,
    const int2* __restrict__ spair,
    const int* __restrict__ ofs,
    const float* __restrict__ b2,
    float* __restrict__ out,
    int E, int n_nodes)
{
    __shared__ unsigned outbuf[BNODES * D];   // 16KB encoded running max
    __shared__ ushort Hs[TILE * D];           // 16KB h tile (fp16, swizzled)
    __shared__ int colidx[TILE];
    __shared__ int rowidx[TILE];

    const int tid = threadIdx.x;
    const int bucket = blockIdx.x;
    const int base = bucket << 5;
    const int estart = ofs[bucket];
    const int eend = ofs[bucket + 1];

    #pragma unroll
    for (int i = 0; i < 16; ++i) outbuf[tid + i * 256] = 0u;   // lane-distinct banks

    const int l = tid & 63, w = tid >> 6;
    const int l15 = l & 15, lq = l >> 4;
    const int cg = tid & 15, esub = tid >> 4;
    const f16x8 zero = {0, 0, 0, 0, 0, 0, 0, 0};

    for (int t0 = estart; t0 < eend; t0 += TILE) {
        const int n = min(TILE, eend - t0);
        __syncthreads();   // prior tile's epilogue reads of colidx / MFMA reads of Hs done
        if (tid < TILE) {
            int2 p = (tid < n) ? spair[t0 + tid] : make_int2(base, base);
            colidx[tid] = p.x;
            rowidx[tid] = p.y;
        }
        __syncthreads();

        // ---- gather + layer 1: h = relu(Pa'[col] + Pb[row]) -> Hs
        f16x8 va[4], vb[4];
        #pragma unroll
        for (int it = 0; it < 4; ++it) {
            int e = it * 16 + esub;
            int c = colidx[e], r = rowidx[e];
            va[it] = *(const f16x8*)(pab + (size_t)c * NCH + cg * 8);
            vb[it] = *(const f16x8*)(pab + (size_t)r * NCH + 128 + cg * 8);
        }
        #pragma unroll
        for (int it = 0; it < 4; ++it) {
            int e = it * 16 + esub;
            f16x8 h = __builtin_elementwise_max(va[it] + vb[it], zero);
            *(f16x8*)((char*)Hs + e * 256 + ((cg * 16) ^ ((e & 7) << 4))) = h;
        }
        __syncthreads();

        // ---- layer 2: [64 x 128] @ [128 x 128]; wave w owns cols [w*32, w*32+32)
        f32x4 acc[4][2];
        #pragma unroll
        for (int mf = 0; mf < 4; ++mf)
            #pragma unroll
            for (int nf = 0; nf < 2; ++nf)
                acc[mf][nf] = (f32x4){0.f, 0.f, 0.f, 0.f};

        #pragma unroll
        for (int kk = 0; kk < 4; ++kk) {
            f16x8 a[4], b[2];
            #pragma unroll
            for (int mf = 0; mf < 4; ++mf) {
                int row = mf * 16 + l15;
                a[mf] = *(const f16x8*)((const char*)Hs + row * 256 + ((kk * 64 + lq * 16) ^ ((row & 7) << 4)));
            }
            #pragma unroll
            for (int nf = 0; nf < 2; ++nf) {
                int col = w * 32 + nf * 16 + l15;
                b[nf] = *(const f16x8*)(w2t + col * 128 + kk * 32 + lq * 8);
            }
            #pragma unroll
            for (int mf = 0; mf < 4; ++mf)
                #pragma unroll
                for (int nf = 0; nf < 2; ++nf)
                    acc[mf][nf] = __builtin_amdgcn_mfma_f32_16x16x32_f16(a[mf], b[nf], acc[mf][nf], 0, 0, 0);
        }

        // ---- epilogue: encoded LDS atomic max into bucket accumulator
        #pragma unroll
        for (int nf = 0; nf < 2; ++nf) {
            int col = w * 32 + nf * 16 + l15;
            #pragma unroll
            for (int mf = 0; mf < 4; ++mf) {
                #pragma unroll
                for (int r = 0; r < 4; ++r) {
                    int row = mf * 16 + lq * 4 + r;
                    if (row < n) {
                        int node = colidx[row] - base;
                        unsigned bs = __float_as_uint(acc[mf][nf][r]);
                        unsigned enc = (bs & 0x80000000u) ? ~bs : (bs | 0x80000000u);
                        atomicMax(&outbuf[node * D + col], enc);
                    }
                }
            }
        }
    }
    __syncthreads();

    // ---- write 32 nodes x 128 ch, decode + b2, empty -> 0, coalesced float4
    const int n0 = tid >> 3;            // 0..31
    const int c0 = (tid & 7) * 16;      // 16 channels per thread
    const int gnode = base + n0;
    if (gnode < n_nodes) {
        #pragma unroll
        for (int j = 0; j < 4; ++j) {
            float4 o;
            #pragma unroll
            for (int k = 0; k < 4; ++k) {
                int ch = c0 + j * 4 + k;
                unsigned u = outbuf[n0 * D + ch];
                float v;
                if (u == 0u) v = 0.f;
                else {
                    unsigned bs = (u & 0x80000000u) ? (u & 0x7fffffffu) : ~u;
                    v = __uint_as_float(bs) + b2[ch];
                }
                ((float*)&o)[k] = v;
            }
            *(float4*)(out + (size_t)gnode * D + c0 + j * 4) = o;
        }
    }
}

extern "C" void kernel_launch(void* const* d_in, const int* in_sizes, int n_in,
                              void* d_out, int out_size, void* d_ws, size_t ws_size,
                              hipStream_t stream)
{
    const float* x  = (const float*)d_in[0];
    const int* eidx = (const int*)d_in[1];
    const float* W1 = (const float*)d_in[2];
    const float* b1 = (const float*)d_in[3];
    const float* W2 = (const float*)d_in[4];
    const float* b2 = (const float*)d_in[5];

    const int n_nodes = in_sizes[0] / D;
    const int E = in_sizes[1] / 2;
    const int* erow = eidx;        // edge_index[0]
    const int* ecol = eidx + E;    // edge_index[1]

    const int nb = (n_nodes + BNODES - 1) / BNODES;   // 1563 buckets
    const int nbp = (nb + 2) & ~1;                    // padded even (+slack), zeroed

    // ---- workspace layout
    char* ws = (char*)d_ws;
    size_t off = 0;
    ushort* pab = (ushort*)(ws + off);   off += (size_t)n_nodes * NCH * sizeof(ushort);
    off = (off + 255) & ~(size_t)255;
    ushort* w1abt = (ushort*)(ws + off); off += (size_t)NCH * D * sizeof(ushort);
    ushort* w2t = (ushort*)(ws + off);   off += (size_t)D * D * sizeof(ushort);
    off = (off + 255) & ~(size_t)255;
    int* hist = (int*)(ws + off);        off += (size_t)nbp * 4;
    off = (off + 255) & ~(size_t)255;
    int* ofs = (int*)(ws + off);         off += (size_t)(nb + 1) * 4;
    off = (off + 255) & ~(size_t)255;
    int* ocur = (int*)(ws + off);        off += (size_t)nb * 4;
    off = (off + 255) & ~(size_t)255;
    int2* spair = (int2*)(ws + off);     off += (size_t)E * 8;

    float* out = (float*)d_out;

    const int init_work = NCH * D + D * D + nbp;
    init_kernel<<<(init_work + 255) / 256, 256, 0, stream>>>(W1, W2, w1abt, w2t, hist, nbp);

    hist_kernel<<<128, 256, 0, stream>>>(ecol, hist, E, n_nodes, nb);

    scan_kernel<<<1, 1024, 0, stream>>>(hist, ofs, ocur, nb, E);

    scatter_kernel<<<(E + 255) / 256, 256, 0, stream>>>(erow, ecol, ocur, spair, E, n_nodes);

    pab_kernel<<<(n_nodes + 63) / 64, 256, 0, stream>>>(x, w1abt, b1, pab, n_nodes);

    edgeconv_main<<<nb, 256, 0, stream>>>(pab, w2t, spair, ofs, b2, out, E, n_nodes);
}

// Round 7
// 168.192 us; speedup vs baseline: 2.1953x; 1.2003x over previous
//
#include <hip/hip_runtime.h>

typedef __attribute__((ext_vector_type(8))) _Float16 f16x8;
typedef __attribute__((ext_vector_type(4))) _Float16 f16x4;
typedef __attribute__((ext_vector_type(4))) float f32x4;

#define D 128
#define NCH 256       // Pab channels: [0:128)=Pa'=Pa+b1, [128:256)=Pb
#define BNODES 32     // nodes per bucket-block
#define TILE 64       // edges per inner tile in main

static __device__ __forceinline__ ushort f2h(float f) {
    _Float16 h = (_Float16)f;
    return __builtin_bit_cast(ushort, h);
}

// ---------- prep: convert weights + per-node col histogram (hist pre-zeroed by memset) ----------
__global__ void prep_kernel(const float* __restrict__ W1,
                            const float* __restrict__ W2,
                            const int* __restrict__ ecol,
                            ushort* __restrict__ w1abt,
                            ushort* __restrict__ w2t,
                            int* __restrict__ hist,
                            int E, int n_nodes)
{
    int gid = blockIdx.x * blockDim.x + threadIdx.x;
    if (gid < NCH * D) {
        int oc = gid >> 7, k = gid & 127;
        float v;
        if (oc < 128) v = W1[k * D + oc] - W1[(k + 128) * D + oc];
        else          v = W1[(k + 128) * D + (oc - 128)];
        w1abt[gid] = f2h(v);
    } else if (gid < NCH * D + D * D) {
        int id2 = gid - NCH * D;
        int oc = id2 >> 7, k = id2 & 127;
        w2t[id2] = f2h(W2[k * D + oc]);
    } else {
        int e = gid - (NCH * D + D * D);
        if (e < E) {
            int c = ecol[e];
            if ((unsigned)c >= (unsigned)n_nodes) c = 0;
            atomicAdd(&hist[c], 1);
        }
    }
}

// ---------- hierarchical exclusive scan over n_nodes counts ----------
__global__ void scan1_kernel(const int* __restrict__ hist, int* __restrict__ partial, int N)
{
    __shared__ int s[256];
    int tid = threadIdx.x;
    int i = blockIdx.x * 256 + tid;
    s[tid] = (i < N) ? hist[i] : 0;
    __syncthreads();
    #pragma unroll
    for (int off = 128; off > 0; off >>= 1) {
        if (tid < off) s[tid] += s[tid + off];
        __syncthreads();
    }
    if (tid == 0) partial[blockIdx.x] = s[0];
}

__global__ void scan2_kernel(const int* __restrict__ partial, int* __restrict__ bofs,
                             int* __restrict__ ofs, int nb, int n_nodes, int E)
{
    __shared__ int s[256];
    int tid = threadIdx.x;
    int v = (tid < nb) ? partial[tid] : 0;
    s[tid] = v;
    __syncthreads();
    #pragma unroll
    for (int off = 1; off < 256; off <<= 1) {
        int t = (tid >= off) ? s[tid - off] : 0;
        __syncthreads();
        s[tid] += t;
        __syncthreads();
    }
    if (tid < nb) bofs[tid] = s[tid] - v;
    if (tid == 0) ofs[n_nodes] = E;
}

__global__ void scan3_kernel(const int* __restrict__ hist, const int* __restrict__ bofs,
                             int* __restrict__ ofs, int* __restrict__ ocur, int N)
{
    __shared__ int s[256];
    int tid = threadIdx.x;
    int i = blockIdx.x * 256 + tid;
    int v = (i < N) ? hist[i] : 0;
    s[tid] = v;
    __syncthreads();
    #pragma unroll
    for (int off = 1; off < 256; off <<= 1) {
        int t = (tid >= off) ? s[tid - off] : 0;
        __syncthreads();
        s[tid] += t;
        __syncthreads();
    }
    if (i < N) {
        int e = bofs[blockIdx.x] + s[tid] - v;
        ofs[i] = e;
        ocur[i] = e;
    }
}

// ---------- scatter: per-node counting sort (12 collisions/addr avg); emit (col,row) pairs ----------
__global__ void scatter_kernel(const int* __restrict__ erow, const int* __restrict__ ecol,
                               int* __restrict__ ocur,
                               int2* __restrict__ spair,
                               int E, int n_nodes)
{
    int e = blockIdx.x * blockDim.x + threadIdx.x;
    if (e < E) {
        int c = ecol[e];
        if ((unsigned)c >= (unsigned)n_nodes) c = 0;
        int r = erow[e];
        if ((unsigned)r >= (unsigned)n_nodes) r = 0;
        int pos = atomicAdd(&ocur[c], 1);
        spair[pos] = make_int2(c, r);
    }
}

// ---------- Pab = x(fp16) @ [W1a | W1b] (+b1 folded into Pa'), fp16 out ----------
__global__ __launch_bounds__(256) void pab_kernel(
    const float* __restrict__ x,
    const ushort* __restrict__ w1abt,
    const float* __restrict__ b1,
    ushort* __restrict__ pab,
    int n_nodes)
{
    __shared__ ushort A[64 * 128];   // [node][k] fp16, swizzled
    const int tid = threadIdx.x;
    const int base = blockIdx.x * 64;

    #pragma unroll
    for (int it = 0; it < 8; ++it) {
        int idx4 = it * 256 + tid;       // float4 index in 64x128 tile
        int row = idx4 >> 5;
        int c4  = idx4 & 31;
        int node = base + row;
        float4 vx = make_float4(0.f, 0.f, 0.f, 0.f);
        if (node < n_nodes) vx = ((const float4*)x)[(size_t)node * 32 + c4];
        f16x4 o;
        o[0] = (_Float16)vx.x; o[1] = (_Float16)vx.y;
        o[2] = (_Float16)vx.z; o[3] = (_Float16)vx.w;
        *(f16x4*)((char*)A + row * 256 + ((c4 * 8) ^ ((row & 7) << 4))) = o;
    }
    __syncthreads();

    const int l = tid & 63, w = tid >> 6;
    const int l15 = l & 15, lq = l >> 4;

    f32x4 acc[4][4];                 // [channel frag][node frag]
    #pragma unroll
    for (int cf = 0; cf < 4; ++cf)
        #pragma unroll
        for (int rf = 0; rf < 4; ++rf)
            acc[cf][rf] = (f32x4){0.f, 0.f, 0.f, 0.f};

    #pragma unroll
    for (int kk = 0; kk < 4; ++kk) {
        f16x8 a[4], b[4];
        #pragma unroll
        for (int cf = 0; cf < 4; ++cf)
            a[cf] = *(const f16x8*)(w1abt + (w * 64 + cf * 16 + l15) * 128 + kk * 32 + lq * 8);
        #pragma unroll
        for (int rf = 0; rf < 4; ++rf) {
            int row = rf * 16 + l15;
            b[rf] = *(const f16x8*)((const char*)A + row * 256 + ((kk * 64 + lq * 16) ^ ((row & 7) << 4)));
        }
        #pragma unroll
        for (int cf = 0; cf < 4; ++cf)
            #pragma unroll
            for (int rf = 0; rf < 4; ++rf)
                acc[cf][rf] = __builtin_amdgcn_mfma_f32_16x16x32_f16(a[cf], b[rf], acc[cf][rf], 0, 0, 0);
    }

    // D[ch][node]: node = rf*16 + l15 (lane), ch = w*64 + cf*16 + lq*4 + r
    #pragma unroll
    for (int rf = 0; rf < 4; ++rf) {
        int node = base + rf * 16 + l15;
        if (node < n_nodes) {
            #pragma unroll
            for (int cf = 0; cf < 4; ++cf) {
                int ch = w * 64 + cf * 16 + lq * 4;
                float4 bb = (w < 2) ? *(const float4*)(b1 + ch) : make_float4(0.f, 0.f, 0.f, 0.f);
                f16x4 o;
                o[0] = (_Float16)(acc[cf][rf][0] + bb.x);
                o[1] = (_Float16)(acc[cf][rf][1] + bb.y);
                o[2] = (_Float16)(acc[cf][rf][2] + bb.z);
                o[3] = (_Float16)(acc[cf][rf][3] + bb.w);
                *(f16x4*)(pab + (size_t)node * NCH + ch) = o;
            }
        }
    }
}

// ================= main: one block owns one bucket (32 nodes), no global atomics =================
__global__ __launch_bounds__(256, 4) void edgeconv_main(
    const ushort* __restrict__ pab,
    const ushort* __restrict__ w2t,
    const int2* __restrict__ spair,
    const int* __restrict__ nofs,     // node-level offsets [n_nodes+1]
    const float* __restrict__ b2,
    float* __restrict__ out,
    int E, int n_nodes)
{
    __shared__ unsigned outbuf[BNODES * D];   // 16KB encoded running max
    __shared__ ushort Hs[TILE * D];           // 16KB h tile (fp16, swizzled)
    __shared__ int colidx[TILE];
    __shared__ int rowidx[TILE];

    const int tid = threadIdx.x;
    const int bucket = blockIdx.x;
    const int base = bucket << 5;
    const int nend = min(base + BNODES, n_nodes);
    const int estart = nofs[base];
    const int eend = nofs[nend];

    #pragma unroll
    for (int i = 0; i < 16; ++i) outbuf[tid + i * 256] = 0u;   // lane-distinct banks

    const int l = tid & 63, w = tid >> 6;
    const int l15 = l & 15, lq = l >> 4;
    const int cg = tid & 15, esub = tid >> 4;
    const f16x8 zero = {0, 0, 0, 0, 0, 0, 0, 0};

    for (int t0 = estart; t0 < eend; t0 += TILE) {
        const int n = min(TILE, eend - t0);
        __syncthreads();   // prior tile's epilogue reads of colidx / MFMA reads of Hs done
        if (tid < TILE) {
            int2 p = (tid < n) ? spair[t0 + tid] : make_int2(base, base);
            colidx[tid] = p.x;
            rowidx[tid] = p.y;
        }
        __syncthreads();

        // ---- gather + layer 1: h = relu(Pa'[col] + Pb[row]) -> Hs
        f16x8 va[4], vb[4];
        #pragma unroll
        for (int it = 0; it < 4; ++it) {
            int e = it * 16 + esub;
            int c = colidx[e], r = rowidx[e];
            va[it] = *(const f16x8*)(pab + (size_t)c * NCH + cg * 8);
            vb[it] = *(const f16x8*)(pab + (size_t)r * NCH + 128 + cg * 8);
        }
        #pragma unroll
        for (int it = 0; it < 4; ++it) {
            int e = it * 16 + esub;
            f16x8 h = __builtin_elementwise_max(va[it] + vb[it], zero);
            *(f16x8*)((char*)Hs + e * 256 + ((cg * 16) ^ ((e & 7) << 4))) = h;
        }
        __syncthreads();

        // ---- layer 2: [64 x 128] @ [128 x 128]; wave w owns cols [w*32, w*32+32)
        f32x4 acc[4][2];
        #pragma unroll
        for (int mf = 0; mf < 4; ++mf)
            #pragma unroll
            for (int nf = 0; nf < 2; ++nf)
                acc[mf][nf] = (f32x4){0.f, 0.f, 0.f, 0.f};

        #pragma unroll
        for (int kk = 0; kk < 4; ++kk) {
            f16x8 a[4], b[2];
            #pragma unroll
            for (int mf = 0; mf < 4; ++mf) {
                int row = mf * 16 + l15;
                a[mf] = *(const f16x8*)((const char*)Hs + row * 256 + ((kk * 64 + lq * 16) ^ ((row & 7) << 4)));
            }
            #pragma unroll
            for (int nf = 0; nf < 2; ++nf) {
                int col = w * 32 + nf * 16 + l15;
                b[nf] = *(const f16x8*)(w2t + col * 128 + kk * 32 + lq * 8);
            }
            #pragma unroll
            for (int mf = 0; mf < 4; ++mf)
                #pragma unroll
                for (int nf = 0; nf < 2; ++nf)
                    acc[mf][nf] = __builtin_amdgcn_mfma_f32_16x16x32_f16(a[mf], b[nf], acc[mf][nf], 0, 0, 0);
        }

        // ---- epilogue: encoded LDS atomic max into bucket accumulator
        #pragma unroll
        for (int nf = 0; nf < 2; ++nf) {
            int col = w * 32 + nf * 16 + l15;
            #pragma unroll
            for (int mf = 0; mf < 4; ++mf) {
                #pragma unroll
                for (int r = 0; r < 4; ++r) {
                    int row = mf * 16 + lq * 4 + r;
                    if (row < n) {
                        int node = colidx[row] - base;
                        unsigned bs = __float_as_uint(acc[mf][nf][r]);
                        unsigned enc = (bs & 0x80000000u) ? ~bs : (bs | 0x80000000u);
                        atomicMax(&outbuf[node * D + col], enc);
                    }
                }
            }
        }
    }
    __syncthreads();

    // ---- write 32 nodes x 128 ch, decode + b2, empty -> 0, coalesced float4
    const int n0 = tid >> 3;            // 0..31
    const int c0 = (tid & 7) * 16;      // 16 channels per thread
    const int gnode = base + n0;
    if (gnode < n_nodes) {
        #pragma unroll
        for (int j = 0; j < 4; ++j) {
            float4 o;
            #pragma unroll
            for (int k = 0; k < 4; ++k) {
                int ch = c0 + j * 4 + k;
                unsigned u = outbuf[n0 * D + ch];
                float v;
                if (u == 0u) v = 0.f;
                else {
                    unsigned bs = (u & 0x80000000u) ? (u & 0x7fffffffu) : ~u;
                    v = __uint_as_float(bs) + b2[ch];
                }
                ((float*)&o)[k] = v;
            }
            *(float4*)(out + (size_t)gnode * D + c0 + j * 4) = o;
        }
    }
}

extern "C" void kernel_launch(void* const* d_in, const int* in_sizes, int n_in,
                              void* d_out, int out_size, void* d_ws, size_t ws_size,
                              hipStream_t stream)
{
    const float* x  = (const float*)d_in[0];
    const int* eidx = (const int*)d_in[1];
    const float* W1 = (const float*)d_in[2];
    const float* b1 = (const float*)d_in[3];
    const float* W2 = (const float*)d_in[4];
    const float* b2 = (const float*)d_in[5];

    const int n_nodes = in_sizes[0] / D;
    const int E = in_sizes[1] / 2;
    const int* erow = eidx;        // edge_index[0]
    const int* ecol = eidx + E;    // edge_index[1]

    const int nb_scan = (n_nodes + 255) / 256;              // 196 <= 256
    const int nbuckets = (n_nodes + BNODES - 1) / BNODES;   // 1563

    // ---- workspace layout
    char* ws = (char*)d_ws;
    size_t off = 0;
    ushort* pab = (ushort*)(ws + off);   off += (size_t)n_nodes * NCH * sizeof(ushort);
    off = (off + 255) & ~(size_t)255;
    ushort* w1abt = (ushort*)(ws + off); off += (size_t)NCH * D * sizeof(ushort);
    ushort* w2t = (ushort*)(ws + off);   off += (size_t)D * D * sizeof(ushort);
    off = (off + 255) & ~(size_t)255;
    int* hist = (int*)(ws + off);        off += (size_t)n_nodes * 4;
    off = (off + 255) & ~(size_t)255;
    int* nofs = (int*)(ws + off);        off += (size_t)(n_nodes + 1) * 4;
    off = (off + 255) & ~(size_t)255;
    int* ocur = (int*)(ws + off);        off += (size_t)n_nodes * 4;
    off = (off + 255) & ~(size_t)255;
    int* partial = (int*)(ws + off);     off += 256 * 4;
    int* bofs = (int*)(ws + off);        off += 256 * 4;
    off = (off + 255) & ~(size_t)255;
    int2* spair = (int2*)(ws + off);     off += (size_t)E * 8;

    float* out = (float*)d_out;

    hipMemsetAsync(hist, 0, (size_t)n_nodes * sizeof(int), stream);

    const int prep_work = NCH * D + D * D + E;
    prep_kernel<<<(prep_work + 255) / 256, 256, 0, stream>>>(W1, W2, ecol, w1abt, w2t, hist, E, n_nodes);

    scan1_kernel<<<nb_scan, 256, 0, stream>>>(hist, partial, n_nodes);
    scan2_kernel<<<1, 256, 0, stream>>>(partial, bofs, nofs, nb_scan, n_nodes, E);
    scan3_kernel<<<nb_scan, 256, 0, stream>>>(hist, bofs, nofs, ocur, n_nodes);

    scatter_kernel<<<(E + 255) / 256, 256, 0, stream>>>(erow, ecol, ocur, spair, E, n_nodes);

    pab_kernel<<<(n_nodes + 63) / 64, 256, 0, stream>>>(x, w1abt, b1, pab, n_nodes);

    edgeconv_main<<<nbuckets, 256, 0, stream>>>(pab, w2t, spair, nofs, b2, out, E, n_nodes);
}